// Round 15
// baseline (169.580 us; speedup 1.0000x reference)
//
#include <hip/hip_runtime.h>
#include <hip/hip_bf16.h>

// Problem constants
#define B_    8
#define Qn    16
#define S_    4096
#define Hh    32
#define KVH_  8
#define D_    128
#define G_    4
#define ROWS  64          // G_*Qn score rows per (b,kvh)
#define KT    32          // tokens per inner tile
#define NT_TOT (S_ / KT)  // 128 tiles across the sequence
#define NCHUNK 12         // 768 blocks = 256 CU x 3 resident (LDS 50.5 KB)
#define THREADS 256
#define VTS   40          // vt row stride (shorts): 80B, 16B-aligned reads

typedef unsigned int u32;
typedef unsigned short u16;
typedef __attribute__((ext_vector_type(8))) short short8;   // 8 bf16 (4 VGPRs)
typedef __attribute__((ext_vector_type(4))) float f32x4;    // MFMA C/D

__device__ __forceinline__ u16 f2bf(float f){
  union{u32 u; float f;} t; t.f = f; u32 u = t.u;
  return (u16)((u + 0x7fffu + ((u >> 16) & 1u)) >> 16);   // RNE
}
__device__ __forceinline__ float bf2f(u16 h){
  union{u32 x; float f;} t; t.x = ((u32)h) << 16; return t.f;
}
// Quantize to signed nibble value held as bf16 (ints in [-7,7] exact, see R2).
__device__ __forceinline__ u16 qnib(float x, float inv){
  union{float f; u32 u;} t; t.f = rintf(x * inv);
  return (u16)(t.u >> 16);
}

// Async global->LDS DMA: no result register, tracked by vmcnt, NOT drained by
// raw s_barrier. LDS dest = wave-uniform base + lane*16 (linear).
__device__ __forceinline__ void gll16(const float* g, const void* lds){
  __builtin_amdgcn_global_load_lds((const __attribute__((address_space(1))) void*)g,
                                   (__attribute__((address_space(3))) void*)lds,
                                   16, 0, 0);
}
#define SBAR0 __builtin_amdgcn_sched_barrier(0)

// attn_partial: grid (KVH_, NCHUNK, B_) x 256 threads, 3 blocks/CU.
// EXACT R12 loop (straight-line, static vmcnt counts -- R14 lesson: ANY
// branch around gll issues makes outstanding-vmcnt path-dependent and the
// compiler inserts a per-iteration drain, 2x slowdown). Tail prefetch is
// unconditional with clamped address (L2-hot, cheap).
// R15 keeps only the fused split-K reduction (outside the loop).
__global__ __launch_bounds__(THREADS)
__attribute__((amdgpu_waves_per_eu(3)))
void attn_partial(const float* __restrict__ q, const float* __restrict__ k,
                  const float* __restrict__ v, float* __restrict__ part_o,
                  float* __restrict__ part_ml, int* __restrict__ cnt,
                  float* __restrict__ out)
{
  __shared__ __attribute__((aligned(16))) float rawK[KT * D_];  // 16 KB
  __shared__ __attribute__((aligned(16))) float rawV[KT * D_];  // 16 KB
  __shared__ u16   kn[KT * D_];     // 8 KB quantized K, granule-swizzled
  __shared__ u16   vt[D_ * VTS];    // 10 KB quantized V^T, padded rows
  __shared__ float ksc[KT];
  __shared__ float vsc[KT];
  __shared__ int   lastflag;

  const int kvh   = blockIdx.x;                // fastest: DRAM-dense grouping
  const int chunk = blockIdx.y;
  const int b     = blockIdx.z;
  const int tid   = threadIdx.x;
  const int lane  = tid & 63;
  const int w     = tid >> 6;                  // wave id == head group g
  const int l15   = lane & 15;
  const int l4    = lane >> 4;                 // 0..3
  const int t0    = (chunk * NT_TOT) / NCHUNK;
  const int t1    = ((chunk + 1) * NT_TOT) / NCHUNK;
  const float RS = 0.08838834764831844f;       // 1/sqrt(128)

  // quant-phase assignment: thread <-> OWN wave's staged token lt
  const int lt  = tid >> 3;                    // token 0..31 (= 8w + (lane>>3))
  const int qd4 = (tid & 7) * 4;

  // ---- Q fragments (hi/lo bf16 split) straight into registers ----
  short8 qhi[4], qlo[4];
  {
    const int h = kvh * G_ + w;
    const float* qp = q + (((size_t)(b * Qn + l15) * Hh) + h) * (size_t)D_ + (l4 * 8);
    #pragma unroll
    for (int kc = 0; kc < 4; ++kc){
      const float4 a = *(const float4*)(qp + kc * 32);
      const float4 c = *(const float4*)(qp + kc * 32 + 4);
      const float fv[8] = {a.x, a.y, a.z, a.w, c.x, c.y, c.z, c.w};
      #pragma unroll
      for (int i = 0; i < 8; ++i){
        const u16 hi = f2bf(fv[i]);
        qhi[kc][i] = (short)hi;
        qlo[kc][i] = (short)f2bf(fv[i] - bf2f(hi));
      }
    }
  }

  float m_i = -1e30f, l_i = 0.f;               // per-lane, qi = l15 view
  f32x4 acc_o[8];                              // O: col d = df*16+l15, row qi = l4*4+reg
  #pragma unroll
  for (int df = 0; df < 8; ++df) acc_o[df] = (f32x4)0.f;

  // gll mapping (linear): issue j covers granules (w*4+j)*64 + lane,
  // i.e. wave w stages tokens 8w..8w+7 (its own quant tokens).
  const int lhi = lane >> 5, cp = lane & 31;
  int goff[4];
  #pragma unroll
  for (int j = 0; j < 4; ++j){
    const int tokp = (w * 4 + j) * 2 + lhi;
    goff[j] = tokp * (KVH_ * D_) + (cp << 2);
  }
  const size_t tb0 = ((size_t)b * S_) * KVH_ * D_ + (size_t)kvh * D_;
  const char* rawKb = (const char*)rawK;
  const char* rawVb = (const char*)rawV;

  // ---- prologue: issue async staging of tile t0 (K first, then V) ----
  {
    const size_t base = tb0 + (size_t)(t0 * KT) * KVH_ * D_;
    #pragma unroll
    for (int j = 0; j < 4; ++j) gll16(k + base + goff[j], rawKb + (w * 4 + j) * 1024);
    #pragma unroll
    for (int j = 0; j < 4; ++j) gll16(v + base + goff[j], rawVb + (w * 4 + j) * 1024);
  }

  for (int t = t0; t < t1; ++t){
    const int s0 = t * KT;
    const int sn = (s0 + KT <= S_ - KT) ? (s0 + KT) : (S_ - KT);  // clamped t+1
    const size_t base_n = tb0 + (size_t)sn * KVH_ * D_;

    __builtin_amdgcn_s_barrier();                      // bar1: prev reads done
    SBAR0;

    // ---- K_t landed (oldest 4 of this wave's 8 glls); V_t still flying ----
    asm volatile("s_waitcnt vmcnt(4)" ::: "memory"); SBAR0;
    float4 kr[4];
    #pragma unroll
    for (int m = 0; m < 4; ++m)
      kr[m] = *(const float4*)(rawK + lt * D_ + qd4 + m * 32);
    asm volatile("s_waitcnt lgkmcnt(0)" ::: "memory"); SBAR0;

    // ---- own rawK region free -> issue K(t+1) (flies across everything) ----
    #pragma unroll
    for (int j = 0; j < 4; ++j) gll16(k + base_n + goff[j], rawKb + (w * 4 + j) * 1024);
    SBAR0;

    // ---- quant K -> kn (swizzled) + kscale (V_t delivery hides under this) ----
    {
      float am = 0.f;
      #pragma unroll
      for (int m = 0; m < 4; ++m)
        am = fmaxf(am, fmaxf(fmaxf(fabsf(kr[m].x), fabsf(kr[m].y)),
                             fmaxf(fabsf(kr[m].z), fabsf(kr[m].w))));
      am = fmaxf(am, __shfl_xor(am, 1));
      am = fmaxf(am, __shfl_xor(am, 2));
      am = fmaxf(am, __shfl_xor(am, 4));
      const float sc = fmaxf(am * (1.f / 7.f), 1e-8f);
      if ((tid & 7) == 0) ksc[lt] = sc;
      const float inv = 1.f / sc;
      #pragma unroll
      for (int m = 0; m < 4; ++m){
        const int d0 = qd4 + m * 32;
        const int idx = lt * D_ + ((((d0 >> 3) ^ (lt & 7)) << 3) | (d0 & 7));
        *(ushort4*)&kn[idx] = make_ushort4(qnib(kr[m].x, inv), qnib(kr[m].y, inv),
                                           qnib(kr[m].z, inv), qnib(kr[m].w, inv));
      }
    }

    // ---- V_t landed (K(t+1) flying) ----
    asm volatile("s_waitcnt vmcnt(4)" ::: "memory"); SBAR0;
    float4 vr[4];
    #pragma unroll
    for (int m = 0; m < 4; ++m)
      vr[m] = *(const float4*)(rawV + lt * D_ + qd4 + m * 32);
    asm volatile("s_waitcnt lgkmcnt(0)" ::: "memory"); SBAR0;

    // ---- own rawV region free -> issue V(t+1) ----
    #pragma unroll
    for (int j = 0; j < 4; ++j) gll16(v + base_n + goff[j], rawVb + (w * 4 + j) * 1024);
    SBAR0;

    // ---- quant V -> vt (transposed, padded rows) + vscale ----
    {
      float am = 0.f;
      #pragma unroll
      for (int m = 0; m < 4; ++m)
        am = fmaxf(am, fmaxf(fmaxf(fabsf(vr[m].x), fabsf(vr[m].y)),
                             fmaxf(fabsf(vr[m].z), fabsf(vr[m].w))));
      am = fmaxf(am, __shfl_xor(am, 1));
      am = fmaxf(am, __shfl_xor(am, 2));
      am = fmaxf(am, __shfl_xor(am, 4));
      const float sc = fmaxf(am * (1.f / 7.f), 1e-8f);
      if ((tid & 7) == 0) vsc[lt] = sc;
      const float inv = 1.f / sc;
      #pragma unroll
      for (int m = 0; m < 4; ++m){
        const int d0 = qd4 + m * 32;
        vt[(d0 + 0) * VTS + lt] = qnib(vr[m].x, inv);
        vt[(d0 + 1) * VTS + lt] = qnib(vr[m].y, inv);
        vt[(d0 + 2) * VTS + lt] = qnib(vr[m].z, inv);
        vt[(d0 + 3) * VTS + lt] = qnib(vr[m].w, inv);
      }
    }
    asm volatile("s_waitcnt lgkmcnt(0)" ::: "memory"); SBAR0;
    __builtin_amdgcn_s_barrier();                      // bar2: kn/vt/scales visible
    SBAR0;

    // ---- QK^T (swapped): st[cf] C[tok=l4*4+r+16cf][qi=l15] ----
    f32x4 st[2];
    st[0] = (f32x4)0.f; st[1] = (f32x4)0.f;
    __builtin_amdgcn_s_setprio(1);
    #pragma unroll
    for (int kc = 0; kc < 4; ++kc){
      #pragma unroll
      for (int cf = 0; cf < 2; ++cf){
        const int tok = cf * 16 + l15;
        const int gr  = kc * 4 + l4;           // d-granule 0..15
        const short8 kf = *(const short8*)&kn[tok * D_ + ((gr ^ (tok & 7)) << 3)];
        st[cf] = __builtin_amdgcn_mfma_f32_16x16x32_bf16(kf, qhi[kc], st[cf], 0, 0, 0);
        st[cf] = __builtin_amdgcn_mfma_f32_16x16x32_bf16(kf, qlo[kc], st[cf], 0, 0, 0);
      }
    }
    __builtin_amdgcn_s_setprio(0);

    // ---- online softmax in [tok][qi] layout (R7-verified) ----
    float ksr[2][4], vsv[2][4];
    #pragma unroll
    for (int cf = 0; cf < 2; ++cf){
      const float4 ks = *(const float4*)&ksc[cf * 16 + l4 * 4];
      const float4 vs = *(const float4*)&vsc[cf * 16 + l4 * 4];
      ksr[cf][0] = ks.x * RS; ksr[cf][1] = ks.y * RS;
      ksr[cf][2] = ks.z * RS; ksr[cf][3] = ks.w * RS;
      vsv[cf][0] = vs.x; vsv[cf][1] = vs.y; vsv[cf][2] = vs.z; vsv[cf][3] = vs.w;
    }
    const bool need_mask = (s0 + KT > S_ - Qn);      // only the last tile
    float x[2][4]; float rm = -1e30f;
    #pragma unroll
    for (int cf = 0; cf < 2; ++cf)
      #pragma unroll
      for (int r = 0; r < 4; ++r){
        float xx = st[cf][r] * ksr[cf][r];
        if (need_mask && (s0 + cf * 16 + l4 * 4 + r > S_ - Qn + l15)) xx = -1e30f;
        x[cf][r] = xx; rm = fmaxf(rm, xx);
      }
    rm = fmaxf(rm, __shfl_xor(rm, 16));
    rm = fmaxf(rm, __shfl_xor(rm, 32));
    const float mn  = fmaxf(m_i, rm);
    const float fac = __expf(m_i - mn);
    m_i = mn;
    float p[2][4]; float rs = 0.f;
    #pragma unroll
    for (int cf = 0; cf < 2; ++cf)
      #pragma unroll
      for (int r = 0; r < 4; ++r){
        p[cf][r] = __expf(x[cf][r] - mn);
        rs += p[cf][r];
      }
    rs += __shfl_xor(rs, 16);
    rs += __shfl_xor(rs, 32);
    l_i = l_i * fac + rs;

    // P~ = bf16(p * vscale[tok]) packed, then 8-shfl transpose to PV A-frag
    u32 pk0[2], pk1[2];
    #pragma unroll
    for (int rp = 0; rp < 2; ++rp){
      pk0[rp] = (u32)f2bf(p[0][2*rp] * vsv[0][2*rp]) | ((u32)f2bf(p[0][2*rp+1] * vsv[0][2*rp+1]) << 16);
      pk1[rp] = (u32)f2bf(p[1][2*rp] * vsv[1][2*rp]) | ((u32)f2bf(p[1][2*rp+1] * vsv[1][2*rp+1]) << 16);
    }
    const int s0L = ((l4 & 1) * 2) * 16 + l15;
    const int s1L = s0L + 16;
    const u32 a00 = __shfl((int)pk0[0], s0L), a01 = __shfl((int)pk0[1], s0L);
    const u32 a02 = __shfl((int)pk0[0], s1L), a03 = __shfl((int)pk0[1], s1L);
    const u32 a10 = __shfl((int)pk1[0], s0L), a11 = __shfl((int)pk1[1], s0L);
    const u32 a12 = __shfl((int)pk1[0], s1L), a13 = __shfl((int)pk1[1], s1L);
    const bool hi = (l4 >= 2);
    union { uint4 u; short8 s; } pfu;
    pfu.u = make_uint4(hi ? a10 : a00, hi ? a11 : a01,
                       hi ? a12 : a02, hi ? a13 : a03);
    const short8 pf = pfu.s;

    f32x4 facv;
    #pragma unroll
    for (int r = 0; r < 4; ++r) facv[r] = __shfl(fac, l4 * 4 + r);
    #pragma unroll
    for (int df = 0; df < 8; ++df) acc_o[df] *= facv;

    // ---- PV via MFMA: A = P~ (in-register), B = V^T tile ----
    __builtin_amdgcn_s_setprio(1);
    #pragma unroll
    for (int df = 0; df < 8; ++df){
      const int d = df * 16 + l15;
      const short8 vf = *(const short8*)&vt[d * VTS + l4 * 8];
      acc_o[df] = __builtin_amdgcn_mfma_f32_16x16x32_bf16(pf, vf, acc_o[df], 0, 0, 0);
    }
    __builtin_amdgcn_s_setprio(0);
    // no end barrier: kn/vt rewrites gated by next iter's bar1; raw refills
    // are wave-local.
  }

  asm volatile("s_waitcnt vmcnt(0)" ::: "memory"); SBAR0;  // drain dangling DMA

  // ---- write partials (unnormalized O, m, l) ----
  {
    const size_t base = (((size_t)b * KVH_ + kvh) * (size_t)NCHUNK + chunk) * ROWS;
    #pragma unroll
    for (int r = 0; r < 4; ++r){
      const int qrow = (w << 4) + (l4 << 2) + r;
      #pragma unroll
      for (int df = 0; df < 8; ++df)
        part_o[(base + qrow) * D_ + df * 16 + l15] = acc_o[df][r];
    }
    if (l4 == 0){                              // lanes 0..15 hold qi=l15 state
      part_ml[(base + (w << 4) + l15) * 2 + 0] = m_i;
      part_ml[(base + (w << 4) + l15) * 2 + 1] = l_i;
    }
  }

  // ---- fused split-K reduction: last-arriving block per (b,kvh) reduces ----
  __syncthreads();                             // all partial stores issued
  if (tid == 0){
    __threadfence();                           // release partials device-wide
    const int old = __hip_atomic_fetch_add(&cnt[b * KVH_ + kvh], 1,
                                           __ATOMIC_ACQ_REL,
                                           __HIP_MEMORY_SCOPE_AGENT);
    lastflag = (old == NCHUNK - 1);
  }
  __syncthreads();
  if (lastflag){
    __threadfence();                           // acquire all blocks' partials
    const size_t rbase = ((size_t)b * KVH_ + kvh) * (size_t)NCHUNK;
    const int row  = tid >> 2;                 // 0..63
    const int dseg = (tid & 3) * 32;           // 4 x 32-d segments
    float M = -1e30f;
    #pragma unroll 4
    for (int c = 0; c < NCHUNK; ++c)
      M = fmaxf(M, part_ml[((rbase + c) * ROWS + row) * 2 + 0]);
    f32x4 acc[8];
    #pragma unroll
    for (int j = 0; j < 8; ++j) acc[j] = (f32x4)0.f;
    float lt_sum = 0.f;
    for (int c = 0; c < NCHUNK; ++c){
      const size_t ri = (rbase + c) * ROWS + row;
      const float mm = part_ml[ri * 2 + 0];
      const float ll = part_ml[ri * 2 + 1];
      const float wt = __expf(mm - M);
      lt_sum += wt * ll;
      const float* src = part_o + ri * D_ + dseg;
      #pragma unroll
      for (int j = 0; j < 8; ++j){
        const float4 pv = *(const float4*)(src + j * 4);
        acc[j][0] += wt * pv.x; acc[j][1] += wt * pv.y;
        acc[j][2] += wt * pv.z; acc[j][3] += wt * pv.w;
      }
    }
    const float invl = 1.f / lt_sum;
    const int g = row >> 4, qi = row & 15;
    float* dst = out + (((size_t)b * Qn + qi) * Hh + kvh * G_ + g) * (size_t)D_ + dseg;
    #pragma unroll
    for (int j = 0; j < 8; ++j){
      float4 o4;
      o4.x = acc[j][0] * invl; o4.y = acc[j][1] * invl;
      o4.z = acc[j][2] * invl; o4.w = acc[j][3] * invl;
      *(float4*)(dst + j * 4) = o4;
    }
  }
}

extern "C" void kernel_launch(void* const* d_in, const int* in_sizes, int n_in,
                              void* d_out, int out_size, void* d_ws, size_t ws_size,
                              hipStream_t stream)
{
  const float* q = (const float*)d_in[0];
  const float* k = (const float*)d_in[1];
  const float* v = (const float*)d_in[2];
  // d_in[3] = block_table: identity permutation round-trip; ECC encode/decode
  // with no injected errors is the identity on the nibble -> fake-quant only.
  float* out = (float*)d_out;

  // Workspace: part_o (25.2 MB f32) | part_ml (0.8 MB) | cnt (256 B)
  float* part_o  = (float*)d_ws;
  float* part_ml = part_o + (size_t)B_ * KVH_ * NCHUNK * ROWS * D_;
  int*   cnt     = (int*)(part_ml + (size_t)B_ * KVH_ * NCHUNK * ROWS * 2);

  hipMemsetAsync(cnt, 0, B_ * KVH_ * sizeof(int), stream);

  attn_partial<<<dim3(KVH_, NCHUNK, B_), THREADS, 0, stream>>>(
      q, k, v, part_o, part_ml, cnt, out);
}

// Round 16
// 62.011 us; speedup vs baseline: 2.7347x; 2.7347x over previous
//
#include <hip/hip_runtime.h>
#include <hip/hip_bf16.h>

// Problem constants
#define B_    8
#define Qn    16
#define S_    4096
#define Hh    32
#define KVH_  8
#define D_    128
#define G_    4
#define ROWS  64          // G_*Qn score rows per (b,kvh)
#define KT    32          // tokens per inner tile
#define NT_TOT (S_ / KT)  // 128 tiles across the sequence
#define NCHUNK 12         // 768 blocks = 256 CU x 3 resident (LDS 50.5 KB)
#define THREADS 256
#define VTS   40          // vt row stride (shorts): 80B, 16B-aligned reads

typedef unsigned int u32;
typedef unsigned short u16;
typedef __attribute__((ext_vector_type(8))) short short8;   // 8 bf16 (4 VGPRs)
typedef __attribute__((ext_vector_type(4))) float f32x4;    // MFMA C/D

__device__ __forceinline__ u16 f2bf(float f){
  union{u32 u; float f;} t; t.f = f; u32 u = t.u;
  return (u16)((u + 0x7fffu + ((u >> 16) & 1u)) >> 16);   // RNE
}
__device__ __forceinline__ float bf2f(u16 h){
  union{u32 x; float f;} t; t.x = ((u32)h) << 16; return t.f;
}
// Quantize to signed nibble value held as bf16 (ints in [-7,7] exact, see R2).
__device__ __forceinline__ u16 qnib(float x, float inv){
  union{float f; u32 u;} t; t.f = rintf(x * inv);
  return (u16)(t.u >> 16);
}

// Async global->LDS DMA: no result register, tracked by vmcnt, NOT drained by
// raw s_barrier. LDS dest = wave-uniform base + lane*16 (linear).
__device__ __forceinline__ void gll16(const float* g, const void* lds){
  __builtin_amdgcn_global_load_lds((const __attribute__((address_space(1))) void*)g,
                                   (__attribute__((address_space(3))) void*)lds,
                                   16, 0, 0);
}
#define SBAR0 __builtin_amdgcn_sched_barrier(0)

// attn_partial: grid (KVH_, NCHUNK, B_) x 256 threads, 3 blocks/CU.
// EXACT R12 structure (best measured: 63.65 us total). Straight-line loop,
// static vmcnt counts, counted waits vmcnt(4), wave-local raw refills,
// 2 barriers/iter. R14/R15 lesson: NO device-scope atomics/fences in this
// kernel -- fused reduction halved loop throughput. Keep the 2-kernel split.
__global__ __launch_bounds__(THREADS)
__attribute__((amdgpu_waves_per_eu(3)))
void attn_partial(const float* __restrict__ q, const float* __restrict__ k,
                  const float* __restrict__ v, float* __restrict__ part_o,
                  float* __restrict__ part_ml)
{
  __shared__ __attribute__((aligned(16))) float rawK[KT * D_];  // 16 KB
  __shared__ __attribute__((aligned(16))) float rawV[KT * D_];  // 16 KB
  __shared__ u16   kn[KT * D_];     // 8 KB quantized K, granule-swizzled
  __shared__ u16   vt[D_ * VTS];    // 10 KB quantized V^T, padded rows
  __shared__ float ksc[KT];
  __shared__ float vsc[KT];

  const int kvh   = blockIdx.x;                // fastest: DRAM-dense grouping
  const int chunk = blockIdx.y;
  const int b     = blockIdx.z;
  const int tid   = threadIdx.x;
  const int lane  = tid & 63;
  const int w     = tid >> 6;                  // wave id == head group g
  const int l15   = lane & 15;
  const int l4    = lane >> 4;                 // 0..3
  const int t0    = (chunk * NT_TOT) / NCHUNK;
  const int t1    = ((chunk + 1) * NT_TOT) / NCHUNK;
  const float RS = 0.08838834764831844f;       // 1/sqrt(128)

  // quant-phase assignment: thread <-> OWN wave's staged token lt
  const int lt  = tid >> 3;                    // token 0..31 (= 8w + (lane>>3))
  const int qd4 = (tid & 7) * 4;

  // ---- Q fragments (hi/lo bf16 split) straight into registers ----
  short8 qhi[4], qlo[4];
  {
    const int h = kvh * G_ + w;
    const float* qp = q + (((size_t)(b * Qn + l15) * Hh) + h) * (size_t)D_ + (l4 * 8);
    #pragma unroll
    for (int kc = 0; kc < 4; ++kc){
      const float4 a = *(const float4*)(qp + kc * 32);
      const float4 c = *(const float4*)(qp + kc * 32 + 4);
      const float fv[8] = {a.x, a.y, a.z, a.w, c.x, c.y, c.z, c.w};
      #pragma unroll
      for (int i = 0; i < 8; ++i){
        const u16 hi = f2bf(fv[i]);
        qhi[kc][i] = (short)hi;
        qlo[kc][i] = (short)f2bf(fv[i] - bf2f(hi));
      }
    }
  }

  float m_i = -1e30f, l_i = 0.f;               // per-lane, qi = l15 view
  f32x4 acc_o[8];                              // O: col d = df*16+l15, row qi = l4*4+reg
  #pragma unroll
  for (int df = 0; df < 8; ++df) acc_o[df] = (f32x4)0.f;

  // gll mapping (linear): issue j covers granules (w*4+j)*64 + lane,
  // i.e. wave w stages tokens 8w..8w+7 (its own quant tokens).
  const int lhi = lane >> 5, cp = lane & 31;
  int goff[4];
  #pragma unroll
  for (int j = 0; j < 4; ++j){
    const int tokp = (w * 4 + j) * 2 + lhi;
    goff[j] = tokp * (KVH_ * D_) + (cp << 2);
  }
  const size_t tb0 = ((size_t)b * S_) * KVH_ * D_ + (size_t)kvh * D_;
  const char* rawKb = (const char*)rawK;
  const char* rawVb = (const char*)rawV;

  // ---- prologue: issue async staging of tile t0 (K first, then V) ----
  {
    const size_t base = tb0 + (size_t)(t0 * KT) * KVH_ * D_;
    #pragma unroll
    for (int j = 0; j < 4; ++j) gll16(k + base + goff[j], rawKb + (w * 4 + j) * 1024);
    #pragma unroll
    for (int j = 0; j < 4; ++j) gll16(v + base + goff[j], rawVb + (w * 4 + j) * 1024);
  }

  for (int t = t0; t < t1; ++t){
    const int s0 = t * KT;
    const int sn = (s0 + KT <= S_ - KT) ? (s0 + KT) : (S_ - KT);  // clamped t+1
    const size_t base_n = tb0 + (size_t)sn * KVH_ * D_;

    __builtin_amdgcn_s_barrier();                      // bar1: prev reads done
    SBAR0;

    // ---- K_t landed (oldest 4 of this wave's 8 glls); V_t still flying ----
    asm volatile("s_waitcnt vmcnt(4)" ::: "memory"); SBAR0;
    float4 kr[4];
    #pragma unroll
    for (int m = 0; m < 4; ++m)
      kr[m] = *(const float4*)(rawK + lt * D_ + qd4 + m * 32);
    asm volatile("s_waitcnt lgkmcnt(0)" ::: "memory"); SBAR0;

    // ---- own rawK region free -> issue K(t+1) (flies across everything) ----
    #pragma unroll
    for (int j = 0; j < 4; ++j) gll16(k + base_n + goff[j], rawKb + (w * 4 + j) * 1024);
    SBAR0;

    // ---- quant K -> kn (swizzled) + kscale (V_t delivery hides under this) ----
    {
      float am = 0.f;
      #pragma unroll
      for (int m = 0; m < 4; ++m)
        am = fmaxf(am, fmaxf(fmaxf(fabsf(kr[m].x), fabsf(kr[m].y)),
                             fmaxf(fabsf(kr[m].z), fabsf(kr[m].w))));
      am = fmaxf(am, __shfl_xor(am, 1));
      am = fmaxf(am, __shfl_xor(am, 2));
      am = fmaxf(am, __shfl_xor(am, 4));
      const float sc = fmaxf(am * (1.f / 7.f), 1e-8f);
      if ((tid & 7) == 0) ksc[lt] = sc;
      const float inv = 1.f / sc;
      #pragma unroll
      for (int m = 0; m < 4; ++m){
        const int d0 = qd4 + m * 32;
        const int idx = lt * D_ + ((((d0 >> 3) ^ (lt & 7)) << 3) | (d0 & 7));
        *(ushort4*)&kn[idx] = make_ushort4(qnib(kr[m].x, inv), qnib(kr[m].y, inv),
                                           qnib(kr[m].z, inv), qnib(kr[m].w, inv));
      }
    }

    // ---- V_t landed (K(t+1) flying) ----
    asm volatile("s_waitcnt vmcnt(4)" ::: "memory"); SBAR0;
    float4 vr[4];
    #pragma unroll
    for (int m = 0; m < 4; ++m)
      vr[m] = *(const float4*)(rawV + lt * D_ + qd4 + m * 32);
    asm volatile("s_waitcnt lgkmcnt(0)" ::: "memory"); SBAR0;

    // ---- own rawV region free -> issue V(t+1) ----
    #pragma unroll
    for (int j = 0; j < 4; ++j) gll16(v + base_n + goff[j], rawVb + (w * 4 + j) * 1024);
    SBAR0;

    // ---- quant V -> vt (transposed, padded rows) + vscale ----
    {
      float am = 0.f;
      #pragma unroll
      for (int m = 0; m < 4; ++m)
        am = fmaxf(am, fmaxf(fmaxf(fabsf(vr[m].x), fabsf(vr[m].y)),
                             fmaxf(fabsf(vr[m].z), fabsf(vr[m].w))));
      am = fmaxf(am, __shfl_xor(am, 1));
      am = fmaxf(am, __shfl_xor(am, 2));
      am = fmaxf(am, __shfl_xor(am, 4));
      const float sc = fmaxf(am * (1.f / 7.f), 1e-8f);
      if ((tid & 7) == 0) vsc[lt] = sc;
      const float inv = 1.f / sc;
      #pragma unroll
      for (int m = 0; m < 4; ++m){
        const int d0 = qd4 + m * 32;
        vt[(d0 + 0) * VTS + lt] = qnib(vr[m].x, inv);
        vt[(d0 + 1) * VTS + lt] = qnib(vr[m].y, inv);
        vt[(d0 + 2) * VTS + lt] = qnib(vr[m].z, inv);
        vt[(d0 + 3) * VTS + lt] = qnib(vr[m].w, inv);
      }
    }
    asm volatile("s_waitcnt lgkmcnt(0)" ::: "memory"); SBAR0;
    __builtin_amdgcn_s_barrier();                      // bar2: kn/vt/scales visible
    SBAR0;

    // ---- QK^T (swapped): st[cf] C[tok=l4*4+r+16cf][qi=l15] ----
    f32x4 st[2];
    st[0] = (f32x4)0.f; st[1] = (f32x4)0.f;
    __builtin_amdgcn_s_setprio(1);
    #pragma unroll
    for (int kc = 0; kc < 4; ++kc){
      #pragma unroll
      for (int cf = 0; cf < 2; ++cf){
        const int tok = cf * 16 + l15;
        const int gr  = kc * 4 + l4;           // d-granule 0..15
        const short8 kf = *(const short8*)&kn[tok * D_ + ((gr ^ (tok & 7)) << 3)];
        st[cf] = __builtin_amdgcn_mfma_f32_16x16x32_bf16(kf, qhi[kc], st[cf], 0, 0, 0);
        st[cf] = __builtin_amdgcn_mfma_f32_16x16x32_bf16(kf, qlo[kc], st[cf], 0, 0, 0);
      }
    }
    __builtin_amdgcn_s_setprio(0);

    // ---- online softmax in [tok][qi] layout (R7-verified) ----
    float ksr[2][4], vsv[2][4];
    #pragma unroll
    for (int cf = 0; cf < 2; ++cf){
      const float4 ks = *(const float4*)&ksc[cf * 16 + l4 * 4];
      const float4 vs = *(const float4*)&vsc[cf * 16 + l4 * 4];
      ksr[cf][0] = ks.x * RS; ksr[cf][1] = ks.y * RS;
      ksr[cf][2] = ks.z * RS; ksr[cf][3] = ks.w * RS;
      vsv[cf][0] = vs.x; vsv[cf][1] = vs.y; vsv[cf][2] = vs.z; vsv[cf][3] = vs.w;
    }
    const bool need_mask = (s0 + KT > S_ - Qn);      // only the last tile
    float x[2][4]; float rm = -1e30f;
    #pragma unroll
    for (int cf = 0; cf < 2; ++cf)
      #pragma unroll
      for (int r = 0; r < 4; ++r){
        float xx = st[cf][r] * ksr[cf][r];
        if (need_mask && (s0 + cf * 16 + l4 * 4 + r > S_ - Qn + l15)) xx = -1e30f;
        x[cf][r] = xx; rm = fmaxf(rm, xx);
      }
    rm = fmaxf(rm, __shfl_xor(rm, 16));
    rm = fmaxf(rm, __shfl_xor(rm, 32));
    const float mn  = fmaxf(m_i, rm);
    const float fac = __expf(m_i - mn);
    m_i = mn;
    float p[2][4]; float rs = 0.f;
    #pragma unroll
    for (int cf = 0; cf < 2; ++cf)
      #pragma unroll
      for (int r = 0; r < 4; ++r){
        p[cf][r] = __expf(x[cf][r] - mn);
        rs += p[cf][r];
      }
    rs += __shfl_xor(rs, 16);
    rs += __shfl_xor(rs, 32);
    l_i = l_i * fac + rs;

    // P~ = bf16(p * vscale[tok]) packed, then 8-shfl transpose to PV A-frag
    u32 pk0[2], pk1[2];
    #pragma unroll
    for (int rp = 0; rp < 2; ++rp){
      pk0[rp] = (u32)f2bf(p[0][2*rp] * vsv[0][2*rp]) | ((u32)f2bf(p[0][2*rp+1] * vsv[0][2*rp+1]) << 16);
      pk1[rp] = (u32)f2bf(p[1][2*rp] * vsv[1][2*rp]) | ((u32)f2bf(p[1][2*rp+1] * vsv[1][2*rp+1]) << 16);
    }
    const int s0L = ((l4 & 1) * 2) * 16 + l15;
    const int s1L = s0L + 16;
    const u32 a00 = __shfl((int)pk0[0], s0L), a01 = __shfl((int)pk0[1], s0L);
    const u32 a02 = __shfl((int)pk0[0], s1L), a03 = __shfl((int)pk0[1], s1L);
    const u32 a10 = __shfl((int)pk1[0], s0L), a11 = __shfl((int)pk1[1], s0L);
    const u32 a12 = __shfl((int)pk1[0], s1L), a13 = __shfl((int)pk1[1], s1L);
    const bool hi = (l4 >= 2);
    union { uint4 u; short8 s; } pfu;
    pfu.u = make_uint4(hi ? a10 : a00, hi ? a11 : a01,
                       hi ? a12 : a02, hi ? a13 : a03);
    const short8 pf = pfu.s;

    f32x4 facv;
    #pragma unroll
    for (int r = 0; r < 4; ++r) facv[r] = __shfl(fac, l4 * 4 + r);
    #pragma unroll
    for (int df = 0; df < 8; ++df) acc_o[df] *= facv;

    // ---- PV via MFMA: A = P~ (in-register), B = V^T tile ----
    __builtin_amdgcn_s_setprio(1);
    #pragma unroll
    for (int df = 0; df < 8; ++df){
      const int d = df * 16 + l15;
      const short8 vf = *(const short8*)&vt[d * VTS + l4 * 8];
      acc_o[df] = __builtin_amdgcn_mfma_f32_16x16x32_bf16(pf, vf, acc_o[df], 0, 0, 0);
    }
    __builtin_amdgcn_s_setprio(0);
    // no end barrier: kn/vt rewrites gated by next iter's bar1; raw refills
    // are wave-local.
  }

  asm volatile("s_waitcnt vmcnt(0)" ::: "memory"); SBAR0;  // drain dangling DMA

  // ---- write partials (unnormalized O, m, l) ----
  {
    const size_t base = (((size_t)b * KVH_ + kvh) * (size_t)NCHUNK + chunk) * ROWS;
    #pragma unroll
    for (int r = 0; r < 4; ++r){
      const int qrow = (w << 4) + (l4 << 2) + r;
      #pragma unroll
      for (int df = 0; df < 8; ++df)
        part_o[(base + qrow) * D_ + df * 16 + l15] = acc_o[df][r];
    }
    if (l4 == 0){                              // lanes 0..15 hold qi=l15 state
      part_ml[(base + (w << 4) + l15) * 2 + 0] = m_i;
      part_ml[(base + (w << 4) + l15) * 2 + 1] = l_i;
    }
  }
}

// attn_reduce: vectorized split-K combine. 2048 blocks x 64 threads; each
// lane owns (row = 2*blockIdx.x + lane/32, d4 = (lane%32)*4): 12 float2 ml
// loads + 12 float4 partial loads, all coalesced (32 lanes x 16B = 512B).
__global__ __launch_bounds__(64)
void attn_reduce(const float* __restrict__ part_o, const float* __restrict__ part_ml,
                 float* __restrict__ out)
{
  const int lane = threadIdx.x;                // 0..63
  const int row  = blockIdx.x * 2 + (lane >> 5);   // 0..63
  const int kvh  = blockIdx.y;
  const int b    = blockIdx.z;
  const int d4   = (lane & 31) * 4;
  const size_t base = ((size_t)b * KVH_ + kvh) * (size_t)NCHUNK;

  float mv[NCHUNK], lv[NCHUNK];
  float M = -1e30f;
  #pragma unroll
  for (int c = 0; c < NCHUNK; ++c){
    const float2 ml = *(const float2*)&part_ml[((base + c) * ROWS + row) * 2];
    mv[c] = ml.x; lv[c] = ml.y;
    M = fmaxf(M, ml.x);
  }
  float4 acc = make_float4(0.f, 0.f, 0.f, 0.f);
  float lt = 0.f;
  #pragma unroll
  for (int c = 0; c < NCHUNK; ++c){
    const float wgt = __expf(mv[c] - M);
    lt += wgt * lv[c];
    const float4 pv = *(const float4*)&part_o[((base + c) * ROWS + row) * D_ + d4];
    acc.x += wgt * pv.x; acc.y += wgt * pv.y;
    acc.z += wgt * pv.z; acc.w += wgt * pv.w;
  }
  const float invl = 1.f / lt;
  const int g = row >> 4, qi = row & 15;
  float4 o4;
  o4.x = acc.x * invl; o4.y = acc.y * invl;
  o4.z = acc.z * invl; o4.w = acc.w * invl;
  *(float4*)&out[(((size_t)b * Qn + qi) * Hh + kvh * G_ + g) * (size_t)D_ + d4] = o4;
}

extern "C" void kernel_launch(void* const* d_in, const int* in_sizes, int n_in,
                              void* d_out, int out_size, void* d_ws, size_t ws_size,
                              hipStream_t stream)
{
  const float* q = (const float*)d_in[0];
  const float* k = (const float*)d_in[1];
  const float* v = (const float*)d_in[2];
  // d_in[3] = block_table: identity permutation round-trip; ECC encode/decode
  // with no injected errors is the identity on the nibble -> fake-quant only.
  float* out = (float*)d_out;

  // part_o: B*KVH*NCHUNK*ROWS*D floats = 25.2 MB (fits d_ws as in R3-R15).
  float* part_o  = (float*)d_ws;
  float* part_ml = part_o + (size_t)B_ * KVH_ * NCHUNK * ROWS * D_;

  // kvh fastest -> the 8 kvh-slices of one (b,chunk) are co-dispatched and
  // together cover each 4KB K/V line densely (DRAM row locality).
  attn_partial<<<dim3(KVH_, NCHUNK, B_), THREADS, 0, stream>>>(q, k, v, part_o, part_ml);
  attn_reduce<<<dim3(ROWS / 2, KVH_, B_), 64, 0, stream>>>(part_o, part_ml, out);
}

// Round 17
// 60.349 us; speedup vs baseline: 2.8100x; 1.0275x over previous
//
#include <hip/hip_runtime.h>
#include <hip/hip_bf16.h>

// Problem constants
#define B_    8
#define Qn    16
#define S_    4096
#define Hh    32
#define KVH_  8
#define D_    128
#define G_    4
#define ROWS  64          // G_*Qn score rows per (b,kvh)
#define KT    32          // tokens per inner tile
#define NT_TOT (S_ / KT)  // 128 tiles across the sequence
#define NCHUNK 12         // 768 blocks = 256 CU x 3 resident (LDS 50.5 KB)
#define THREADS 256
#define VTS   40          // vt row stride (shorts): 80B, 16B-aligned reads

typedef unsigned int u32;
typedef unsigned short u16;
typedef __attribute__((ext_vector_type(8))) short short8;     // 8 bf16 (4 VGPRs)
typedef __attribute__((ext_vector_type(4))) float f32x4;      // MFMA C/D
typedef __attribute__((ext_vector_type(8))) _Float16 half8;   // 16B of fp16

__device__ __forceinline__ u16 f2bf(float f){
  union{u32 u; float f;} t; t.f = f; u32 u = t.u;
  return (u16)((u + 0x7fffu + ((u >> 16) & 1u)) >> 16);   // RNE
}
__device__ __forceinline__ float bf2f(u16 h){
  union{u32 x; float f;} t; t.x = ((u32)h) << 16; return t.f;
}
// Quantize to signed nibble value held as bf16 (ints in [-7,7] exact, see R2).
__device__ __forceinline__ u16 qnib(float x, float inv){
  union{float f; u32 u;} t; t.f = rintf(x * inv);
  return (u16)(t.u >> 16);
}

// Async global->LDS DMA: no result register, tracked by vmcnt, NOT drained by
// raw s_barrier. LDS dest = wave-uniform base + lane*16 (linear).
__device__ __forceinline__ void gll16(const float* g, const void* lds){
  __builtin_amdgcn_global_load_lds((const __attribute__((address_space(1))) void*)g,
                                   (__attribute__((address_space(3))) void*)lds,
                                   16, 0, 0);
}
#define SBAR0 __builtin_amdgcn_sched_barrier(0)

// attn_partial: grid (KVH_, NCHUNK, B_) x 256 threads, 3 blocks/CU.
// EXACT R12 pipeline (best measured). R17 deltas, both branch-free:
//   (1) part_o stored as fp16 (halves the partial round-trip, ~25 MB);
//   (2) tail prefetch clamps to its OWN tile (select, not branch -> static
//       vmcnt counts preserved; last iteration's glls are L2-hot re-fetches,
//       saving ~24.6 MB of HBM for the next chunk's data it never uses).
__global__ __launch_bounds__(THREADS)
__attribute__((amdgpu_waves_per_eu(3)))
void attn_partial(const float* __restrict__ q, const float* __restrict__ k,
                  const float* __restrict__ v, _Float16* __restrict__ part_o,
                  float* __restrict__ part_ml)
{
  __shared__ __attribute__((aligned(16))) float rawK[KT * D_];  // 16 KB
  __shared__ __attribute__((aligned(16))) float rawV[KT * D_];  // 16 KB
  __shared__ u16   kn[KT * D_];     // 8 KB quantized K, granule-swizzled
  __shared__ u16   vt[D_ * VTS];    // 10 KB quantized V^T, padded rows
  __shared__ float ksc[KT];
  __shared__ float vsc[KT];

  const int kvh   = blockIdx.x;                // fastest: DRAM-dense grouping
  const int chunk = blockIdx.y;
  const int b     = blockIdx.z;
  const int tid   = threadIdx.x;
  const int lane  = tid & 63;
  const int w     = tid >> 6;                  // wave id == head group g
  const int l15   = lane & 15;
  const int l4    = lane >> 4;                 // 0..3
  const int t0    = (chunk * NT_TOT) / NCHUNK;
  const int t1    = ((chunk + 1) * NT_TOT) / NCHUNK;
  const float RS = 0.08838834764831844f;       // 1/sqrt(128)

  // quant-phase assignment: thread <-> OWN wave's staged token lt
  const int lt  = tid >> 3;                    // token 0..31 (= 8w + (lane>>3))
  const int qd4 = (tid & 7) * 4;

  // ---- Q fragments (hi/lo bf16 split) straight into registers ----
  short8 qhi[4], qlo[4];
  {
    const int h = kvh * G_ + w;
    const float* qp = q + (((size_t)(b * Qn + l15) * Hh) + h) * (size_t)D_ + (l4 * 8);
    #pragma unroll
    for (int kc = 0; kc < 4; ++kc){
      const float4 a = *(const float4*)(qp + kc * 32);
      const float4 c = *(const float4*)(qp + kc * 32 + 4);
      const float fv[8] = {a.x, a.y, a.z, a.w, c.x, c.y, c.z, c.w};
      #pragma unroll
      for (int i = 0; i < 8; ++i){
        const u16 hi = f2bf(fv[i]);
        qhi[kc][i] = (short)hi;
        qlo[kc][i] = (short)f2bf(fv[i] - bf2f(hi));
      }
    }
  }

  float m_i = -1e30f, l_i = 0.f;               // per-lane, qi = l15 view
  f32x4 acc_o[8];                              // O: col d = df*16+l15, row qi = l4*4+reg
  #pragma unroll
  for (int df = 0; df < 8; ++df) acc_o[df] = (f32x4)0.f;

  // gll mapping (linear): issue j covers granules (w*4+j)*64 + lane,
  // i.e. wave w stages tokens 8w..8w+7 (its own quant tokens).
  const int lhi = lane >> 5, cp = lane & 31;
  int goff[4];
  #pragma unroll
  for (int j = 0; j < 4; ++j){
    const int tokp = (w * 4 + j) * 2 + lhi;
    goff[j] = tokp * (KVH_ * D_) + (cp << 2);
  }
  const size_t tb0 = ((size_t)b * S_) * KVH_ * D_ + (size_t)kvh * D_;
  const char* rawKb = (const char*)rawK;
  const char* rawVb = (const char*)rawV;

  // ---- prologue: issue async staging of tile t0 (K first, then V) ----
  {
    const size_t base = tb0 + (size_t)(t0 * KT) * KVH_ * D_;
    #pragma unroll
    for (int j = 0; j < 4; ++j) gll16(k + base + goff[j], rawKb + (w * 4 + j) * 1024);
    #pragma unroll
    for (int j = 0; j < 4; ++j) gll16(v + base + goff[j], rawVb + (w * 4 + j) * 1024);
  }

  for (int t = t0; t < t1; ++t){
    const int s0 = t * KT;
    // Self-clamped tail: last iteration re-prefetches its OWN tile (L2-hot).
    // Select, not branch: vmcnt counts stay statically known (R14 lesson).
    const int sn = (t + 1 < t1) ? (s0 + KT) : s0;
    const size_t base_n = tb0 + (size_t)sn * KVH_ * D_;

    __builtin_amdgcn_s_barrier();                      // bar1: prev reads done
    SBAR0;

    // ---- K_t landed (oldest 4 of this wave's 8 glls); V_t still flying ----
    asm volatile("s_waitcnt vmcnt(4)" ::: "memory"); SBAR0;
    float4 kr[4];
    #pragma unroll
    for (int m = 0; m < 4; ++m)
      kr[m] = *(const float4*)(rawK + lt * D_ + qd4 + m * 32);
    asm volatile("s_waitcnt lgkmcnt(0)" ::: "memory"); SBAR0;

    // ---- own rawK region free -> issue K(t+1) (flies across everything) ----
    #pragma unroll
    for (int j = 0; j < 4; ++j) gll16(k + base_n + goff[j], rawKb + (w * 4 + j) * 1024);
    SBAR0;

    // ---- quant K -> kn (swizzled) + kscale (V_t delivery hides under this) ----
    {
      float am = 0.f;
      #pragma unroll
      for (int m = 0; m < 4; ++m)
        am = fmaxf(am, fmaxf(fmaxf(fabsf(kr[m].x), fabsf(kr[m].y)),
                             fmaxf(fabsf(kr[m].z), fabsf(kr[m].w))));
      am = fmaxf(am, __shfl_xor(am, 1));
      am = fmaxf(am, __shfl_xor(am, 2));
      am = fmaxf(am, __shfl_xor(am, 4));
      const float sc = fmaxf(am * (1.f / 7.f), 1e-8f);
      if ((tid & 7) == 0) ksc[lt] = sc;
      const float inv = 1.f / sc;
      #pragma unroll
      for (int m = 0; m < 4; ++m){
        const int d0 = qd4 + m * 32;
        const int idx = lt * D_ + ((((d0 >> 3) ^ (lt & 7)) << 3) | (d0 & 7));
        *(ushort4*)&kn[idx] = make_ushort4(qnib(kr[m].x, inv), qnib(kr[m].y, inv),
                                           qnib(kr[m].z, inv), qnib(kr[m].w, inv));
      }
    }

    // ---- V_t landed (K(t+1) flying) ----
    asm volatile("s_waitcnt vmcnt(4)" ::: "memory"); SBAR0;
    float4 vr[4];
    #pragma unroll
    for (int m = 0; m < 4; ++m)
      vr[m] = *(const float4*)(rawV + lt * D_ + qd4 + m * 32);
    asm volatile("s_waitcnt lgkmcnt(0)" ::: "memory"); SBAR0;

    // ---- own rawV region free -> issue V(t+1) ----
    #pragma unroll
    for (int j = 0; j < 4; ++j) gll16(v + base_n + goff[j], rawVb + (w * 4 + j) * 1024);
    SBAR0;

    // ---- quant V -> vt (transposed, padded rows) + vscale ----
    {
      float am = 0.f;
      #pragma unroll
      for (int m = 0; m < 4; ++m)
        am = fmaxf(am, fmaxf(fmaxf(fabsf(vr[m].x), fabsf(vr[m].y)),
                             fmaxf(fabsf(vr[m].z), fabsf(vr[m].w))));
      am = fmaxf(am, __shfl_xor(am, 1));
      am = fmaxf(am, __shfl_xor(am, 2));
      am = fmaxf(am, __shfl_xor(am, 4));
      const float sc = fmaxf(am * (1.f / 7.f), 1e-8f);
      if ((tid & 7) == 0) vsc[lt] = sc;
      const float inv = 1.f / sc;
      #pragma unroll
      for (int m = 0; m < 4; ++m){
        const int d0 = qd4 + m * 32;
        vt[(d0 + 0) * VTS + lt] = qnib(vr[m].x, inv);
        vt[(d0 + 1) * VTS + lt] = qnib(vr[m].y, inv);
        vt[(d0 + 2) * VTS + lt] = qnib(vr[m].z, inv);
        vt[(d0 + 3) * VTS + lt] = qnib(vr[m].w, inv);
      }
    }
    asm volatile("s_waitcnt lgkmcnt(0)" ::: "memory"); SBAR0;
    __builtin_amdgcn_s_barrier();                      // bar2: kn/vt/scales visible
    SBAR0;

    // ---- QK^T (swapped): st[cf] C[tok=l4*4+r+16cf][qi=l15] ----
    f32x4 st[2];
    st[0] = (f32x4)0.f; st[1] = (f32x4)0.f;
    __builtin_amdgcn_s_setprio(1);
    #pragma unroll
    for (int kc = 0; kc < 4; ++kc){
      #pragma unroll
      for (int cf = 0; cf < 2; ++cf){
        const int tok = cf * 16 + l15;
        const int gr  = kc * 4 + l4;           // d-granule 0..15
        const short8 kf = *(const short8*)&kn[tok * D_ + ((gr ^ (tok & 7)) << 3)];
        st[cf] = __builtin_amdgcn_mfma_f32_16x16x32_bf16(kf, qhi[kc], st[cf], 0, 0, 0);
        st[cf] = __builtin_amdgcn_mfma_f32_16x16x32_bf16(kf, qlo[kc], st[cf], 0, 0, 0);
      }
    }
    __builtin_amdgcn_s_setprio(0);

    // ---- online softmax in [tok][qi] layout (R7-verified) ----
    float ksr[2][4], vsv[2][4];
    #pragma unroll
    for (int cf = 0; cf < 2; ++cf){
      const float4 ks = *(const float4*)&ksc[cf * 16 + l4 * 4];
      const float4 vs = *(const float4*)&vsc[cf * 16 + l4 * 4];
      ksr[cf][0] = ks.x * RS; ksr[cf][1] = ks.y * RS;
      ksr[cf][2] = ks.z * RS; ksr[cf][3] = ks.w * RS;
      vsv[cf][0] = vs.x; vsv[cf][1] = vs.y; vsv[cf][2] = vs.z; vsv[cf][3] = vs.w;
    }
    const bool need_mask = (s0 + KT > S_ - Qn);      // only the last tile
    float x[2][4]; float rm = -1e30f;
    #pragma unroll
    for (int cf = 0; cf < 2; ++cf)
      #pragma unroll
      for (int r = 0; r < 4; ++r){
        float xx = st[cf][r] * ksr[cf][r];
        if (need_mask && (s0 + cf * 16 + l4 * 4 + r > S_ - Qn + l15)) xx = -1e30f;
        x[cf][r] = xx; rm = fmaxf(rm, xx);
      }
    rm = fmaxf(rm, __shfl_xor(rm, 16));
    rm = fmaxf(rm, __shfl_xor(rm, 32));
    const float mn  = fmaxf(m_i, rm);
    const float fac = __expf(m_i - mn);
    m_i = mn;
    float p[2][4]; float rs = 0.f;
    #pragma unroll
    for (int cf = 0; cf < 2; ++cf)
      #pragma unroll
      for (int r = 0; r < 4; ++r){
        p[cf][r] = __expf(x[cf][r] - mn);
        rs += p[cf][r];
      }
    rs += __shfl_xor(rs, 16);
    rs += __shfl_xor(rs, 32);
    l_i = l_i * fac + rs;

    // P~ = bf16(p * vscale[tok]) packed, then 8-shfl transpose to PV A-frag
    u32 pk0[2], pk1[2];
    #pragma unroll
    for (int rp = 0; rp < 2; ++rp){
      pk0[rp] = (u32)f2bf(p[0][2*rp] * vsv[0][2*rp]) | ((u32)f2bf(p[0][2*rp+1] * vsv[0][2*rp+1]) << 16);
      pk1[rp] = (u32)f2bf(p[1][2*rp] * vsv[1][2*rp]) | ((u32)f2bf(p[1][2*rp+1] * vsv[1][2*rp+1]) << 16);
    }
    const int s0L = ((l4 & 1) * 2) * 16 + l15;
    const int s1L = s0L + 16;
    const u32 a00 = __shfl((int)pk0[0], s0L), a01 = __shfl((int)pk0[1], s0L);
    const u32 a02 = __shfl((int)pk0[0], s1L), a03 = __shfl((int)pk0[1], s1L);
    const u32 a10 = __shfl((int)pk1[0], s0L), a11 = __shfl((int)pk1[1], s0L);
    const u32 a12 = __shfl((int)pk1[0], s1L), a13 = __shfl((int)pk1[1], s1L);
    const bool hi = (l4 >= 2);
    union { uint4 u; short8 s; } pfu;
    pfu.u = make_uint4(hi ? a10 : a00, hi ? a11 : a01,
                       hi ? a12 : a02, hi ? a13 : a03);
    const short8 pf = pfu.s;

    f32x4 facv;
    #pragma unroll
    for (int r = 0; r < 4; ++r) facv[r] = __shfl(fac, l4 * 4 + r);
    #pragma unroll
    for (int df = 0; df < 8; ++df) acc_o[df] *= facv;

    // ---- PV via MFMA: A = P~ (in-register), B = V^T tile ----
    __builtin_amdgcn_s_setprio(1);
    #pragma unroll
    for (int df = 0; df < 8; ++df){
      const int d = df * 16 + l15;
      const short8 vf = *(const short8*)&vt[d * VTS + l4 * 8];
      acc_o[df] = __builtin_amdgcn_mfma_f32_16x16x32_bf16(pf, vf, acc_o[df], 0, 0, 0);
    }
    __builtin_amdgcn_s_setprio(0);
    // no end barrier: kn/vt rewrites gated by next iter's bar1; raw refills
    // are wave-local.
  }

  asm volatile("s_waitcnt vmcnt(0)" ::: "memory"); SBAR0;  // drain dangling DMA

  // ---- write partials: O as fp16 (range: |O|<=~700 << 65504), m/l as f32 ----
  {
    const size_t base = (((size_t)b * KVH_ + kvh) * (size_t)NCHUNK + chunk) * ROWS;
    #pragma unroll
    for (int r = 0; r < 4; ++r){
      const int qrow = (w << 4) + (l4 << 2) + r;
      #pragma unroll
      for (int df = 0; df < 8; ++df)
        part_o[(base + qrow) * D_ + df * 16 + l15] = (_Float16)acc_o[df][r];
    }
    if (l4 == 0){                              // lanes 0..15 hold qi=l15 state
      part_ml[(base + (w << 4) + l15) * 2 + 0] = m_i;
      part_ml[(base + (w << 4) + l15) * 2 + 1] = l_i;
    }
  }
}

// attn_reduce: fp16-partial split-K combine. 1024 blocks x 64 threads; lane
// owns (row = 4*blockIdx.x + lane/16, d8 = (lane%16)*8): NCHUNK half8 loads
// (16B, fully coalesced: 16 lanes x 16B = 256B/row) accumulated in f32.
__global__ __launch_bounds__(64)
void attn_reduce(const _Float16* __restrict__ part_o, const float* __restrict__ part_ml,
                 float* __restrict__ out)
{
  const int lane = threadIdx.x;                // 0..63
  const int row  = blockIdx.x * 4 + (lane >> 4);   // 0..63
  const int kvh  = blockIdx.y;
  const int b    = blockIdx.z;
  const int d8   = (lane & 15) * 8;
  const size_t base = ((size_t)b * KVH_ + kvh) * (size_t)NCHUNK;

  float mv[NCHUNK], lv[NCHUNK];
  float M = -1e30f;
  #pragma unroll
  for (int c = 0; c < NCHUNK; ++c){
    const float2 ml = *(const float2*)&part_ml[((base + c) * ROWS + row) * 2];
    mv[c] = ml.x; lv[c] = ml.y;
    M = fmaxf(M, ml.x);
  }
  float acc[8];
  #pragma unroll
  for (int j = 0; j < 8; ++j) acc[j] = 0.f;
  float lt = 0.f;
  #pragma unroll
  for (int c = 0; c < NCHUNK; ++c){
    const float wgt = __expf(mv[c] - M);
    lt += wgt * lv[c];
    const half8 pv = *(const half8*)&part_o[((base + c) * ROWS + row) * D_ + d8];
    #pragma unroll
    for (int j = 0; j < 8; ++j) acc[j] += wgt * (float)pv[j];
  }
  const float invl = 1.f / lt;
  const int g = row >> 4, qi = row & 15;
  float* dst = out + (((size_t)b * Qn + qi) * Hh + kvh * G_ + g) * (size_t)D_ + d8;
  float4 o0, o1;
  o0.x = acc[0] * invl; o0.y = acc[1] * invl; o0.z = acc[2] * invl; o0.w = acc[3] * invl;
  o1.x = acc[4] * invl; o1.y = acc[5] * invl; o1.z = acc[6] * invl; o1.w = acc[7] * invl;
  *(float4*)dst       = o0;
  *(float4*)(dst + 4) = o1;
}

extern "C" void kernel_launch(void* const* d_in, const int* in_sizes, int n_in,
                              void* d_out, int out_size, void* d_ws, size_t ws_size,
                              hipStream_t stream)
{
  const float* q = (const float*)d_in[0];
  const float* k = (const float*)d_in[1];
  const float* v = (const float*)d_in[2];
  // d_in[3] = block_table: identity permutation round-trip; ECC encode/decode
  // with no injected errors is the identity on the nibble -> fake-quant only.
  float* out = (float*)d_out;

  // Workspace: part_o (12.6 MB fp16) | part_ml (0.8 MB f32)
  _Float16* part_o  = (_Float16*)d_ws;
  float*    part_ml = (float*)(part_o + (size_t)B_ * KVH_ * NCHUNK * ROWS * D_);

  // kvh fastest -> the 8 kvh-slices of one (b,chunk) are co-dispatched and
  // together cover each 4KB K/V line densely (DRAM row locality).
  attn_partial<<<dim3(KVH_, NCHUNK, B_), THREADS, 0, stream>>>(q, k, v, part_o, part_ml);
  attn_reduce<<<dim3(ROWS / 4, KVH_, B_), 64, 0, stream>>>(part_o, part_ml, out);
}